// Round 13
// baseline (317.914 us; speedup 1.0000x reference)
//
#include <hip/hip_runtime.h>
#include <hip/hip_bf16.h>
#include <math.h>

typedef __bf16 bf16x8 __attribute__((ext_vector_type(8)));
typedef float floatx4 __attribute__((ext_vector_type(4)));
typedef float float4v __attribute__((ext_vector_type(4)));
typedef float float2v __attribute__((ext_vector_type(2)));
typedef unsigned short ushortx4 __attribute__((ext_vector_type(4)));
typedef unsigned short ushortx8 __attribute__((ext_vector_type(8)));

__device__ __forceinline__ unsigned short f2bf(float f) {
    unsigned int u = __builtin_bit_cast(unsigned int, f);
    u += 0x7FFFu + ((u >> 16) & 1u);
    return (unsigned short)(u >> 16);
}
__device__ __forceinline__ float bf2f(unsigned short h) {
    unsigned int u = ((unsigned int)h) << 16;
    return __builtin_bit_cast(float, u);
}

__device__ __forceinline__ void gload_lds16(const void* g, void* l) {
    __builtin_amdgcn_global_load_lds(
        (const __attribute__((address_space(1))) unsigned int*)g,
        (__attribute__((address_space(3))) unsigned int*)l, 16, 0, 0);
}

// ---------------------------------------------------------------------------
// cast: out[i] = bf16(in[i]), 8 elems/thread
// ---------------------------------------------------------------------------
__global__ __launch_bounds__(256) void cast_bf16_kernel(
    const float* __restrict__ in, unsigned short* __restrict__ out, long n8)
{
    long i = (long)blockIdx.x * 256 + threadIdx.x;
    long stride = (long)gridDim.x * 256;
    for (; i < n8; i += stride) {
        float4v a = reinterpret_cast<const float4v*>(in)[2 * i];
        float4v b = reinterpret_cast<const float4v*>(in)[2 * i + 1];
        ushortx8 h;
        #pragma unroll
        for (int q = 0; q < 4; ++q) { h[q] = f2bf(a[q]); h[4 + q] = f2bf(b[q]); }
        reinterpret_cast<ushortx8*>(out)[i] = h;
    }
}

// ---------------------------------------------------------------------------
// prep: W1e[ci*90 + tap*10 + co] = w1[co,ci,di,dj]   (tap = di*3+dj)
//       w23[tap*10 + c10]        = sum_c5 w3[c5] * w2[c5,c10,di,dj]
// ---------------------------------------------------------------------------
__global__ __launch_bounds__(256) void prep_kernel(
    const float* __restrict__ w1, const float* __restrict__ w2,
    const float* __restrict__ w3, float* __restrict__ W1e,
    float* __restrict__ w23)
{
    for (int idx = threadIdx.x; idx < 4590; idx += 256) {
        int ci = idx / 90, rem = idx % 90;
        int tap = rem / 10, co = rem % 10;
        int di = tap / 3, dj = tap % 3;
        W1e[idx] = w1[((co * 51 + ci) * 3 + di) * 3 + dj];
    }
    if (threadIdx.x < 90) {
        int tap = threadIdx.x / 10, c10 = threadIdx.x % 10;
        int di = tap / 3, dj = tap % 3;
        float s = 0.f;
        #pragma unroll
        for (int c5 = 0; c5 < 5; ++c5)
            s = fmaf(w3[c5], w2[((c5 * 10 + c10) * 3 + di) * 3 + dj], s);
        w23[threadIdx.x] = s;
    }
}

// ---------------------------------------------------------------------------
// transpose_all: 4 weight transposes (f32 [R][C] -> bf16 [C][R]) in one
// launch; linear block id decodes matrix + (bx,by).
//   [0,4096)   Wc   R=4096 C=1024 (bx=id&31,  by=id>>5)
//   [4096,5120) Wou1 R=1024 C=1024
//   [5120,6144) Wofc R=1024 C=1024
//   [6144,10240) Wdec R=1024 C=4096 (bx=id&127, by=id>>7)
// ---------------------------------------------------------------------------
__global__ __launch_bounds__(256) void transpose_all(
    const float* __restrict__ Wc, const float* __restrict__ Wou1,
    const float* __restrict__ Wofc, const float* __restrict__ Wdec,
    unsigned short* __restrict__ Wcb, unsigned short* __restrict__ Wou1b,
    unsigned short* __restrict__ Wofcb, unsigned short* __restrict__ Wdecb)
{
    __shared__ float t[32][33];
    int id = blockIdx.x;
    const float* in; unsigned short* out; int R, C, bx, by;
    if (id < 4096)      { in = Wc;   out = Wcb;   R = 4096; C = 1024;
                          bx = id & 31;  by = id >> 5; }
    else if (id < 5120) { id -= 4096; in = Wou1; out = Wou1b; R = 1024; C = 1024;
                          bx = id & 31;  by = id >> 5; }
    else if (id < 6144) { id -= 5120; in = Wofc; out = Wofcb; R = 1024; C = 1024;
                          bx = id & 31;  by = id >> 5; }
    else                { id -= 6144; in = Wdec; out = Wdecb; R = 1024; C = 4096;
                          bx = id & 127; by = id >> 7; }
    const int tx = threadIdx.x & 31;
    const int ty = threadIdx.x >> 5;
    const int r0 = by * 32, c0 = bx * 32;
    #pragma unroll
    for (int k = 0; k < 4; ++k)
        t[ty + k * 8][tx] = in[(size_t)(r0 + ty + k * 8) * C + c0 + tx];
    __syncthreads();
    #pragma unroll
    for (int k = 0; k < 4; ++k)
        out[(size_t)(c0 + ty + k * 8) * R + r0 + tx] = f2bf(t[tx][ty + k * 8]);
}

// ---------------------------------------------------------------------------
// fp1: Fp1[p][t] = sum_ci freq[p][ci] * W1e[ci][t]
// ---------------------------------------------------------------------------
__global__ __launch_bounds__(256) void fp1_kernel(
    const float* __restrict__ freq, const float* __restrict__ W1e,
    float* __restrict__ Fp1)
{
    __shared__ float W1s[4590];
    for (int idx = threadIdx.x; idx < 4590; idx += 256)
        W1s[idx] = W1e[idx];
    __syncthreads();
    int p = blockIdx.x * 256 + threadIdx.x;
    if (p >= 22801) return;
    float2v acc[45];
    #pragma unroll
    for (int t = 0; t < 45; ++t) { acc[t][0] = 0.f; acc[t][1] = 0.f; }
    const float* fr = freq + (size_t)p * 51;
    for (int ci = 0; ci < 51; ++ci) {
        float v = fr[ci];
        const float2v* wrow = reinterpret_cast<const float2v*>(&W1s[ci * 90]);
        #pragma unroll
        for (int t = 0; t < 45; ++t) {
            float2v w = wrow[t];
            acc[t][0] = fmaf(v, w[0], acc[t][0]);
            acc[t][1] = fmaf(v, w[1], acc[t][1]);
        }
    }
    float2v* out = reinterpret_cast<float2v*>(Fp1 + (size_t)p * 90);
    #pragma unroll
    for (int t = 0; t < 45; ++t) out[t] = acc[t];
}

// ---------------------------------------------------------------------------
// gather: h1[b,pix][c10] = sum_{valid taps} Fp1[pair(i',j')][tap*10 + c10]
// ---------------------------------------------------------------------------
__global__ __launch_bounds__(320) void gather_kernel(
    const int* __restrict__ preds, const float* __restrict__ Fp1,
    float* __restrict__ h1)
{
    __shared__ int pb[80];
    const int b = blockIdx.y;
    const int tid = threadIdx.x;
    if (tid < 80) pb[tid] = preds[b * 80 + tid];
    __syncthreads();
    const int i = blockIdx.x * 4 + tid / 80;
    const int j = tid % 80;
    float2v acc[5];
    #pragma unroll
    for (int q = 0; q < 5; ++q) { acc[q][0] = 0.f; acc[q][1] = 0.f; }
    #pragma unroll
    for (int di = 0; di < 3; ++di) {
        int ii = i + di - 1;
        if (ii < 0 || ii >= 80) continue;
        int pi = pb[ii] * 151;
        #pragma unroll
        for (int dj = 0; dj < 3; ++dj) {
            int jj = j + dj - 1;
            if (jj < 0 || jj >= 80) continue;
            const float2v* row = reinterpret_cast<const float2v*>(
                Fp1 + (size_t)(pi + pb[jj]) * 90 + (di * 3 + dj) * 10);
            #pragma unroll
            for (int q = 0; q < 5; ++q) {
                float2v v = row[q];
                acc[q][0] += v[0];
                acc[q][1] += v[1];
            }
        }
    }
    float2v* out = reinterpret_cast<float2v*>(
        h1 + ((size_t)b * 6400 + i * 80 + j) * 10);
    #pragma unroll
    for (int q = 0; q < 5; ++q) out[q] = acc[q];
}

// ---------------------------------------------------------------------------
// conv23+degree fused: adj = sigmoid(conv over h1); block owns 4 full rows
// -> per-row LDS sum -> deg = rsqrt(1 + rowsum + 1e-5)
// ---------------------------------------------------------------------------
__global__ __launch_bounds__(320) void conv23_deg_kernel(
    const float* __restrict__ h1, const float* __restrict__ w23g,
    float* __restrict__ adj, float* __restrict__ deg)
{
    __shared__ float w23s[90];
    __shared__ float rowv[320];
    const int tid = threadIdx.x;
    if (tid < 90) w23s[tid] = w23g[tid];
    __syncthreads();
    const int b = blockIdx.y;
    const int i = blockIdx.x * 4 + tid / 80;
    const int j = tid % 80;
    float t = 0.f;
    #pragma unroll
    for (int di = 0; di < 3; ++di) {
        int ii = i + di - 1;
        if (ii < 0 || ii >= 80) continue;
        #pragma unroll
        for (int dj = 0; dj < 3; ++dj) {
            int jj = j + dj - 1;
            if (jj < 0 || jj >= 80) continue;
            const float2v* hp = reinterpret_cast<const float2v*>(
                h1 + ((size_t)b * 6400 + ii * 80 + jj) * 10);
            const float* wp = w23s + (di * 3 + dj) * 10;
            #pragma unroll
            for (int q = 0; q < 5; ++q) {
                float2v v = hp[q];
                t = fmaf(v[0], wp[2 * q], t);
                t = fmaf(v[1], wp[2 * q + 1], t);
            }
        }
    }
    float sig = 1.0f / (1.0f + __expf(-t));
    adj[(size_t)b * 6400 + i * 80 + j] = sig;
    rowv[tid] = sig;
    __syncthreads();
    if (tid < 4) {
        float s = 1.0f + 1e-5f;
        #pragma unroll 16
        for (int jj = 0; jj < 80; ++jj) s += rowv[tid * 80 + jj];
        deg[b * 80 + blockIdx.x * 4 + tid] = rsqrtf(s);
    }
}

// ---------------------------------------------------------------------------
// 64x128 GEMM, BK=32, 24 KiB LDS (6 blocks/CU), full-drain dbuf pipeline.
// Grid (M/64, N/128) -> 640 blocks at M=5120,N=1024 (2.5 blocks/CU).
// LDS row-major [row][4 slots], both-sides XOR slot=s^((row>>1)&3)
// (conflict-free, r11-verified). Operand-swapped MFMA; LDS-coalesced
// epilogue: relu -> bf16.
// ---------------------------------------------------------------------------
__global__ __launch_bounds__(256) void gemm64(
    const unsigned short* __restrict__ Ap, const unsigned short* __restrict__ Bt,
    unsigned short* __restrict__ Cp, int M, int N, int lda)
{
    __shared__ __align__(16) unsigned short SS[12288];   // 24 KiB
    unsigned short* Al = SS;          // [2][64*32]
    unsigned short* Bl = SS + 4096;   // [2][128*32]

    const int tid  = threadIdx.x;
    const int bm   = blockIdx.x * 64;
    const int bn   = blockIdx.y * 128;
    const int wave = tid >> 6;
    const int lane = tid & 63;
    const int wm   = (wave >> 1) * 32;
    const int wn   = (wave & 1) * 64;
    const int lr   = lane & 15;
    const int lo   = lane >> 4;
    const int soct = (lo ^ ((lr >> 1) & 3)) * 8;

    floatx4 acc[2][4];
    #pragma unroll
    for (int i = 0; i < 2; ++i)
        #pragma unroll
        for (int j = 0; j < 4; ++j)
            #pragma unroll
            for (int r = 0; r < 4; ++r) acc[i][j][r] = 0.0f;

    auto stage = [&](int buf, int kq) {
        {   // A: 256 chunks (64 rows x 4 slots)
            int r = tid >> 2, s = tid & 3;
            gload_lds16(
                &Ap[(size_t)(bm + r) * lda + kq + ((s ^ ((r >> 1) & 3)) * 8)],
                &Al[buf * 2048 + tid * 8]);
        }
        #pragma unroll
        for (int it = 0; it < 2; ++it) {   // B: 512 chunks
            int idx = tid + it * 256;
            int r = idx >> 2, s = idx & 3;
            gload_lds16(
                &Bt[(size_t)(bn + r) * lda + kq + ((s ^ ((r >> 1) & 3)) * 8)],
                &Bl[buf * 4096 + idx * 8]);
        }
    };

    stage(0, 0);
    __syncthreads();
    const int nt = lda >> 5;
    int cur = 0;
    for (int t = 0; t < nt; ++t) {
        if (t + 1 < nt) stage(cur ^ 1, (t + 1) << 5);
        bf16x8 af[2], bfv[4];
        #pragma unroll
        for (int mi = 0; mi < 2; ++mi)
            af[mi] = *reinterpret_cast<const bf16x8*>(
                &Al[cur * 2048 + (wm + mi * 16 + lr) * 32 + soct]);
        #pragma unroll
        for (int ni = 0; ni < 4; ++ni)
            bfv[ni] = *reinterpret_cast<const bf16x8*>(
                &Bl[cur * 4096 + (wn + ni * 16 + lr) * 32 + soct]);
        #pragma unroll
        for (int mi = 0; mi < 2; ++mi)
            #pragma unroll
            for (int ni = 0; ni < 4; ++ni)
                acc[mi][ni] = __builtin_amdgcn_mfma_f32_16x16x32_bf16(
                    bfv[ni], af[mi], acc[mi][ni], 0, 0, 0);
        __syncthreads();
        cur ^= 1;
    }

    // epilogue: 64x128 bf16 tile in LDS (16 KiB), coalesced stream-out
    #pragma unroll
    for (int mi = 0; mi < 2; ++mi) {
        const int mrow = wm + mi * 16 + lr;
        const int swz = (mrow & 7) << 4;
        #pragma unroll
        for (int ni = 0; ni < 4; ++ni) {
            const int nc = wn + ni * 16 + lo * 4;
            ushortx4 v;
            #pragma unroll
            for (int rr = 0; rr < 4; ++rr)
                v[rr] = f2bf(fmaxf(acc[mi][ni][rr], 0.f));
            *reinterpret_cast<ushortx4*>(
                (char*)SS + ((mrow * 256 + nc * 2) ^ swz)) = v;
        }
    }
    __syncthreads();
    #pragma unroll
    for (int it = 0; it < 4; ++it) {
        int idx = tid + it * 256;
        int r = idx >> 4, c = idx & 15;
        ushortx8 v = *reinterpret_cast<const ushortx8*>(
            (char*)SS + ((r * 256 + c * 16) ^ ((r & 7) << 4)));
        *reinterpret_cast<ushortx8*>(
            &Cp[(size_t)(bm + r) * N + bn + c * 8]) = v;
    }
}

// ---------------------------------------------------------------------------
// 128x128 GEMM, BK=32 — triple-buffered counted-vmcnt pipeline (r12 best).
// MODE 1: relu + bf16 residual Rb -> f32 (two 64-col passes).
// ---------------------------------------------------------------------------
template<int MODE>
__global__ __launch_bounds__(256) void gemm8p(
    const unsigned short* __restrict__ Ap, const unsigned short* __restrict__ Bt,
    void* __restrict__ Cp, const unsigned short* __restrict__ Rb,
    unsigned short* __restrict__ P1,
    int M, int N, int lda, int kh)
{
    __shared__ __align__(16) unsigned short SS[24576];   // 48 KiB
    unsigned short* Al = SS;            // [3][128*32]
    unsigned short* Bl = SS + 12288;    // [3][128*32]

    const int tid  = threadIdx.x;
    const int bm   = blockIdx.x * 128;
    const int bn   = blockIdx.y * 128;
    const int k0   = blockIdx.z * kh;
    const int wave = tid >> 6;
    const int lane = tid & 63;
    const int wm   = (wave >> 1) * 64;
    const int wn   = (wave & 1) * 64;
    const int lr   = lane & 15;
    const int lo   = lane >> 4;
    const int soct = (lo ^ ((lr >> 1) & 3)) * 8;

    floatx4 acc[4][4];
    #pragma unroll
    for (int i = 0; i < 4; ++i)
        #pragma unroll
        for (int j = 0; j < 4; ++j)
            #pragma unroll
            for (int r = 0; r < 4; ++r) acc[i][j][r] = 0.0f;

    auto stageA = [&](int buf, int kq) {
        #pragma unroll
        for (int it = 0; it < 2; ++it) {
            int idx = tid + it * 256;
            int r = idx >> 2, s = idx & 3;
            gload_lds16(
                &Ap[(size_t)(bm + r) * lda + kq + ((s ^ ((r >> 1) & 3)) * 8)],
                &Al[buf * 4096 + idx * 8]);
        }
    };
    auto stageB = [&](int buf, int kq) {
        #pragma unroll
        for (int it = 0; it < 2; ++it) {
            int idx = tid + it * 256;
            int r = idx >> 2, s = idx & 3;
            gload_lds16(
                &Bt[(size_t)(bn + r) * lda + kq + ((s ^ ((r >> 1) & 3)) * 8)],
                &Bl[buf * 4096 + idx * 8]);
        }
    };

    const int nt = kh >> 5;
    stageA(0, k0);
    stageB(0, k0);
    if (nt > 1) stageA(1, k0 + 32);

    for (int t = 0; t < nt; ++t) {
        const int cur = t % 3;
        if (t + 1 < nt) {
            asm volatile("s_waitcnt vmcnt(2)" ::: "memory");
        } else {
            asm volatile("s_waitcnt vmcnt(0)" ::: "memory");
        }
        __builtin_amdgcn_s_barrier();
        __builtin_amdgcn_sched_barrier(0);

        bf16x8 af[4], bf0[2];
        #pragma unroll
        for (int mi = 0; mi < 4; ++mi)
            af[mi] = *reinterpret_cast<const bf16x8*>(
                &Al[cur * 4096 + (wm + mi * 16 + lr) * 32 + soct]);
        #pragma unroll
        for (int ni = 0; ni < 2; ++ni)
            bf0[ni] = *reinterpret_cast<const bf16x8*>(
                &Bl[cur * 4096 + (wn + ni * 16 + lr) * 32 + soct]);
        if (t + 1 < nt) stageB((t + 1) % 3, k0 + ((t + 1) << 5));
        __builtin_amdgcn_sched_barrier(0);
        __builtin_amdgcn_s_barrier();
        __builtin_amdgcn_s_setprio(1);
        #pragma unroll
        for (int mi = 0; mi < 4; ++mi)
            #pragma unroll
            for (int ni = 0; ni < 2; ++ni)
                acc[mi][ni] = __builtin_amdgcn_mfma_f32_16x16x32_bf16(
                    bf0[ni], af[mi], acc[mi][ni], 0, 0, 0);
        __builtin_amdgcn_s_setprio(0);

        bf16x8 bf1[2];
        #pragma unroll
        for (int ni = 0; ni < 2; ++ni)
            bf1[ni] = *reinterpret_cast<const bf16x8*>(
                &Bl[cur * 4096 + (wn + (ni + 2) * 16 + lr) * 32 + soct]);
        if (t + 2 < nt) stageA((t + 2) % 3, k0 + ((t + 2) << 5));
        __builtin_amdgcn_sched_barrier(0);
        __builtin_amdgcn_s_barrier();
        __builtin_amdgcn_s_setprio(1);
        #pragma unroll
        for (int mi = 0; mi < 4; ++mi)
            #pragma unroll
            for (int ni = 0; ni < 2; ++ni)
                acc[mi][ni + 2] = __builtin_amdgcn_mfma_f32_16x16x32_bf16(
                    bf1[ni], af[mi], acc[mi][ni + 2], 0, 0, 0);
        __builtin_amdgcn_s_setprio(0);
    }

    __syncthreads();
    if (MODE == 1) {
        #pragma unroll
        for (int p = 0; p < 2; ++p) {
            if ((wave & 1) == p) {
                #pragma unroll
                for (int mi = 0; mi < 4; ++mi) {
                    const int mrow = wm + mi * 16 + lr;
                    const int swz = (mrow & 7) << 4;
                    #pragma unroll
                    for (int ni = 0; ni < 4; ++ni) {
                        const int nc = ni * 16 + lo * 4;
                        float4v v;
                        #pragma unroll
                        for (int rr = 0; rr < 4; ++rr) v[rr] = acc[mi][ni][rr];
                        *reinterpret_cast<float4v*>(
                            (char*)SS + ((mrow * 256 + nc * 4) ^ swz)) = v;
                    }
                }
            }
            __syncthreads();
            #pragma unroll
            for (int it = 0; it < 8; ++it) {
                int idx = tid + it * 256;
                int r = idx >> 4, c = idx & 15;
                float4v v = *reinterpret_cast<const float4v*>(
                    (char*)SS + ((r * 256 + c * 16) ^ ((r & 7) << 4)));
                size_t off = (size_t)(bm + r) * N + bn + p * 64 + c * 4;
                ushortx4 rv = *reinterpret_cast<const ushortx4*>(&Rb[off]);
                float4v o;
                #pragma unroll
                for (int rr = 0; rr < 4; ++rr)
                    o[rr] = fmaxf(v[rr], 0.f) + bf2f(rv[rr]);
                *reinterpret_cast<float4v*>(&((float*)Cp)[off]) = o;
            }
            if (p == 0) __syncthreads();
        }
    }
}

// ---------------------------------------------------------------------------
// Fallback GEMM (f32 A converted in staging) -> relu bf16 (ws-small path).
// ---------------------------------------------------------------------------
__global__ __launch_bounds__(256) void gemm_f32a(
    const float* __restrict__ Ap, const unsigned short* __restrict__ Bt,
    unsigned short* __restrict__ Cp, int M, int N, int lda)
{
    __shared__ unsigned short Al[2][128 * 40];
    __shared__ unsigned short Bl[2][128 * 32];
    const int tid  = threadIdx.x;
    const int bm   = blockIdx.x * 128;
    const int bn   = blockIdx.y * 128;
    const int wave = tid >> 6;
    const int lane = tid & 63;
    const int wm   = (wave >> 1) * 64;
    const int wn   = (wave & 1) * 64;
    const int lr   = lane & 15;
    const int lk   = (lane >> 4) * 8;
    floatx4 acc[4][4];
    #pragma unroll
    for (int i = 0; i < 4; ++i)
        #pragma unroll
        for (int j = 0; j < 4; ++j)
            #pragma unroll
            for (int r = 0; r < 4; ++r) acc[i][j][r] = 0.0f;
    auto stage = [&](int buf, int k0) {
        #pragma unroll
        for (int it = 0; it < 4; ++it) {
            int idx = tid + it * 256;
            int r = idx >> 3, kc = (idx & 7) * 4;
            float4v v = *reinterpret_cast<const float4v*>(
                &Ap[(size_t)(bm + r) * lda + k0 + kc]);
            ushortx4 h;
            #pragma unroll
            for (int q = 0; q < 4; ++q) h[q] = f2bf(v[q]);
            *reinterpret_cast<ushortx4*>(&Al[buf][r * 40 + kc]) = h;
        }
        #pragma unroll
        for (int it = 0; it < 2; ++it) {
            int idx = tid + it * 256;
            gload_lds16(&Bt[(size_t)(bn + (idx >> 2)) * lda + k0 + (idx & 3) * 8],
                        &Bl[buf][idx * 8]);
        }
    };
    stage(0, 0);
    __syncthreads();
    const int nt = lda >> 5;
    int cur = 0;
    for (int t = 0; t < nt; ++t) {
        if (t + 1 < nt) stage(cur ^ 1, (t + 1) << 5);
        bf16x8 af[4], bfv[4];
        #pragma unroll
        for (int mi = 0; mi < 4; ++mi)
            af[mi] = *reinterpret_cast<const bf16x8*>(
                &Al[cur][(wm + mi * 16 + lr) * 40 + lk]);
        #pragma unroll
        for (int ni = 0; ni < 4; ++ni)
            bfv[ni] = *reinterpret_cast<const bf16x8*>(
                &Bl[cur][(wn + ni * 16 + lr) * 32 + lk]);
        #pragma unroll
        for (int mi = 0; mi < 4; ++mi)
            #pragma unroll
            for (int ni = 0; ni < 4; ++ni)
                acc[mi][ni] = __builtin_amdgcn_mfma_f32_16x16x32_bf16(
                    af[mi], bfv[ni], acc[mi][ni], 0, 0, 0);
        __syncthreads();
        cur ^= 1;
    }
    #pragma unroll
    for (int mi = 0; mi < 4; ++mi)
        #pragma unroll
        for (int ni = 0; ni < 4; ++ni)
            #pragma unroll
            for (int r = 0; r < 4; ++r) {
                int row = bm + wm + mi * 16 + (lane >> 4) * 4 + r;
                int col = bn + wn + ni * 16 + lr;
                Cp[(size_t)row * N + col] = f2bf(fmaxf(acc[mi][ni][r], 0.f));
            }
}

// ---------------------------------------------------------------------------
// Fallback final GEMM with f32 residual (scattered epilogue) — ws-small path.
// ---------------------------------------------------------------------------
__global__ __launch_bounds__(256) void gemm_res_f32(
    const unsigned short* __restrict__ Ap, const unsigned short* __restrict__ Bt,
    float* __restrict__ Cp, const float* __restrict__ Rp, int M, int N, int lda)
{
    __shared__ unsigned short Al[2][128 * 32];
    __shared__ unsigned short Bl[2][128 * 32];
    const int tid  = threadIdx.x;
    const int bm   = blockIdx.x * 128;
    const int bn   = blockIdx.y * 128;
    const int wave = tid >> 6;
    const int lane = tid & 63;
    const int wm   = (wave >> 1) * 64;
    const int wn   = (wave & 1) * 64;
    const int lr   = lane & 15;
    const int lk   = (lane >> 4) * 8;
    floatx4 acc[4][4];
    #pragma unroll
    for (int i = 0; i < 4; ++i)
        #pragma unroll
        for (int j = 0; j < 4; ++j)
            #pragma unroll
            for (int r = 0; r < 4; ++r) acc[i][j][r] = 0.0f;
    auto stage = [&](int buf, int kq) {
        #pragma unroll
        for (int it = 0; it < 2; ++it) {
            int idx = tid + it * 256;
            gload_lds16(&Ap[(size_t)(bm + (idx >> 2)) * lda + kq + (idx & 3) * 8],
                        &Al[buf][idx * 8]);
        }
        #pragma unroll
        for (int it = 0; it < 2; ++it) {
            int idx = tid + it * 256;
            gload_lds16(&Bt[(size_t)(bn + (idx >> 2)) * lda + kq + (idx & 3) * 8],
                        &Bl[buf][idx * 8]);
        }
    };
    stage(0, 0);
    __syncthreads();
    const int nt = lda >> 5;
    int cur = 0;
    for (int t = 0; t < nt; ++t) {
        if (t + 1 < nt) stage(cur ^ 1, (t + 1) << 5);
        bf16x8 af[4], bfv[4];
        #pragma unroll
        for (int mi = 0; mi < 4; ++mi)
            af[mi] = *reinterpret_cast<const bf16x8*>(
                &Al[cur][(wm + mi * 16 + lr) * 32 + lk]);
        #pragma unroll
        for (int ni = 0; ni < 4; ++ni)
            bfv[ni] = *reinterpret_cast<const bf16x8*>(
                &Bl[cur][(wn + ni * 16 + lr) * 32 + lk]);
        #pragma unroll
        for (int mi = 0; mi < 4; ++mi)
            #pragma unroll
            for (int ni = 0; ni < 4; ++ni)
                acc[mi][ni] = __builtin_amdgcn_mfma_f32_16x16x32_bf16(
                    af[mi], bfv[ni], acc[mi][ni], 0, 0, 0);
        __syncthreads();
        cur ^= 1;
    }
    #pragma unroll
    for (int mi = 0; mi < 4; ++mi)
        #pragma unroll
        for (int ni = 0; ni < 4; ++ni)
            #pragma unroll
            for (int r = 0; r < 4; ++r) {
                int row = bm + wm + mi * 16 + (lane >> 4) * 4 + r;
                int col = bn + wn + ni * 16 + lr;
                size_t off = (size_t)row * N + col;
                Cp[off] = fmaxf(acc[mi][ni][r], 0.f) + Rp[off];
            }
}

// ---------------------------------------------------------------------------
// laplacian matmul: ofl[b,n,k] = d[n] * sum_m (adj[n,m]+I)*d[m] * u[m,k]
// ---------------------------------------------------------------------------
__global__ __launch_bounds__(256) void laplacian_kernel(
    const float* __restrict__ adj, const float* __restrict__ deg,
    const unsigned short* __restrict__ u_in, unsigned short* __restrict__ ofl)
{
    __shared__ float wl[6400];
    __shared__ unsigned short ul[80 * 256];
    const int b   = blockIdx.y;
    const int kq  = blockIdx.x;
    const int tid = threadIdx.x;
    const int ko  = tid & 31;
    const int ngrp = tid >> 5;

    const float* ab = adj + (size_t)b * 6400;
    const float* db = deg + b * 80;
    for (int idx = tid; idx < 6400; idx += 256) {
        int n = idx / 80;
        int m = idx - n * 80;
        float w = ab[idx] + (n == m ? 1.0f : 0.0f);
        wl[idx] = w * db[m];
    }
    const unsigned short* ub = u_in + (size_t)b * 80 * 1024 + kq * 256;
    #pragma unroll
    for (int it = 0; it < 10; ++it) {
        int idx = tid + it * 256;
        int m   = idx >> 5;
        int c8  = (idx & 31) * 8;
        *reinterpret_cast<ushortx8*>(&ul[m * 256 + c8]) =
            *reinterpret_cast<const ushortx8*>(&ub[(size_t)m * 1024 + c8]);
    }
    __syncthreads();

    float acc[10][8];
    #pragma unroll
    for (int ni = 0; ni < 10; ++ni)
        #pragma unroll
        for (int q = 0; q < 8; ++q) acc[ni][q] = 0.0f;

    for (int m = 0; m < 80; ++m) {
        ushortx8 uv = *reinterpret_cast<const ushortx8*>(&ul[m * 256 + ko * 8]);
        float uf[8];
        #pragma unroll
        for (int q = 0; q < 8; ++q) uf[q] = bf2f(uv[q]);
        #pragma unroll
        for (int ni = 0; ni < 10; ++ni) {
            float wv = wl[(ngrp * 10 + ni) * 80 + m];
            #pragma unroll
            for (int q = 0; q < 8; ++q)
                acc[ni][q] = fmaf(wv, uf[q], acc[ni][q]);
        }
    }
    #pragma unroll
    for (int ni = 0; ni < 10; ++ni) {
        int n = ngrp * 10 + ni;
        float dn = db[n];
        ushortx8 o;
        #pragma unroll
        for (int q = 0; q < 8; ++q) o[q] = f2bf(acc[ni][q] * dn);
        *reinterpret_cast<ushortx8*>(
            &ofl[((size_t)(b * 80 + n)) * 1024 + kq * 256 + ko * 8]) = o;
    }
}

// ---------------------------------------------------------------------------
extern "C" void kernel_launch(void* const* d_in, const int* in_sizes, int n_in,
                              void* d_out, int out_size, void* d_ws, size_t ws_size,
                              hipStream_t stream)
{
    const float* enc   = (const float*)d_in[0];   // [64,80,4096]
    const int*   preds = (const int*)d_in[1];     // [64,80]
    const float* freq  = (const float*)d_in[2];   // [22801,51]
    const float* Wc    = (const float*)d_in[3];   // [4096,1024]
    const float* Wou1  = (const float*)d_in[4];   // [1024,1024]
    const float* Wofc  = (const float*)d_in[5];   // [1024,1024]
    const float* Wdec  = (const float*)d_in[6];   // [1024,4096]
    const float* w1    = (const float*)d_in[7];   // [10,51,3,3]
    const float* w2    = (const float*)d_in[8];   // [5,10,3,3]
    const float* w3    = (const float*)d_in[9];   // [1,5,1,1]

    const int M = 5120;  // 64*80
    const size_t SLAB = (size_t)M * 1024;          // 5,242,880 elems
    unsigned short* comp  = (unsigned short*)d_ws; // [5120][1024] bf16
    unsigned short* obju  = comp + SLAB;
    unsigned short* r1    = obju + SLAB;           // 16,384,000 B region
    unsigned short* oflu  = r1;
    float*          h1    = (float*)r1;            // [64*6400][10] f32
    unsigned short* r2    = r1 + 8192000;          // 10,485,760 B region
    unsigned short* um    = r2;
    float*          Fp1   = (float*)r2;            // [22801][90] f32
    unsigned short* Wcb   = r2 + SLAB;             // [1024][4096]
    unsigned short* Wou1b = Wcb + (size_t)1024 * 4096;
    unsigned short* Wofcb = Wou1b + (size_t)1024 * 1024;
    unsigned short* Wdecb = Wofcb + (size_t)1024 * 1024;
    float*          W1e   = (float*)(Wdecb + (size_t)4096 * 1024);
    float*          w23   = W1e + 4590;
    float*          adj   = w23 + 90;              // [64][80][80]
    float*          deg   = adj + (size_t)64 * 6400;
    unsigned short* encb  = (unsigned short*)(deg + 5120); // [5120][4096] bf16
    const size_t need_bytes =
        ((size_t)(encb - comp) + (size_t)M * 4096) * sizeof(unsigned short);
    const bool use_encb = ws_size >= need_bytes;

    // --- weight prep (2 launches) ---
    prep_kernel<<<1, 256, 0, stream>>>(w1, w2, w3, W1e, w23);
    transpose_all<<<10240, 256, 0, stream>>>(
        Wc, Wou1, Wofc, Wdec, Wcb, Wou1b, Wofcb, Wdecb);

    // --- adjacency chain (3 launches; degree fused into conv23) ---
    fp1_kernel<<<90, 256, 0, stream>>>(freq, W1e, Fp1);
    gather_kernel<<<dim3(20, 64), 320, 0, stream>>>(preds, Fp1, h1);
    conv23_deg_kernel<<<dim3(20, 64), 320, 0, stream>>>(h1, w23, adj, deg);

    // --- main chain ---
    if (use_encb) {
        cast_bf16_kernel<<<2048, 256, 0, stream>>>(enc, encb, (long)M * 4096 / 8);
        // gemm1: 64x128 tiles, 640 blocks single-shot (no split-K, no reduce)
        gemm64<<<dim3(80, 8), 256, 0, stream>>>(encb, Wcb, comp, M, 1024, 4096);
        gemm64<<<dim3(80, 8), 256, 0, stream>>>(comp, Wou1b, obju, M, 1024, 1024);
        laplacian_kernel<<<dim3(4, 64), 256, 0, stream>>>(adj, deg, obju, oflu);
        gemm64<<<dim3(80, 8), 256, 0, stream>>>(oflu, Wofcb, um, M, 1024, 1024);
        // gemm4: triple-buffer counted-vmcnt pipeline, bf16 residual
        gemm8p<1><<<dim3(40, 32, 1), 256, 0, stream>>>(
            um, Wdecb, d_out, encb, nullptr, M, 4096, 1024, 1024);
    } else {
        gemm_f32a<<<dim3(40, 8), 256, 0, stream>>>(enc, Wcb, comp, M, 1024, 4096);
        gemm64<<<dim3(80, 8), 256, 0, stream>>>(comp, Wou1b, obju, M, 1024, 1024);
        laplacian_kernel<<<dim3(4, 64), 256, 0, stream>>>(adj, deg, obju, oflu);
        gemm64<<<dim3(80, 8), 256, 0, stream>>>(oflu, Wofcb, um, M, 1024, 1024);
        gemm_res_f32<<<dim3(40, 32), 256, 0, stream>>>(
            um, Wdecb, (float*)d_out, enc, M, 4096, 1024);
    }
}

// Round 14
// 308.387 us; speedup vs baseline: 1.0309x; 1.0309x over previous
//
#include <hip/hip_runtime.h>
#include <hip/hip_bf16.h>
#include <math.h>

typedef __bf16 bf16x8 __attribute__((ext_vector_type(8)));
typedef float floatx4 __attribute__((ext_vector_type(4)));
typedef float float4v __attribute__((ext_vector_type(4)));
typedef float float2v __attribute__((ext_vector_type(2)));
typedef unsigned short ushortx4 __attribute__((ext_vector_type(4)));
typedef unsigned short ushortx8 __attribute__((ext_vector_type(8)));

__device__ __forceinline__ unsigned short f2bf(float f) {
    unsigned int u = __builtin_bit_cast(unsigned int, f);
    u += 0x7FFFu + ((u >> 16) & 1u);
    return (unsigned short)(u >> 16);
}
__device__ __forceinline__ float bf2f(unsigned short h) {
    unsigned int u = ((unsigned int)h) << 16;
    return __builtin_bit_cast(float, u);
}

__device__ __forceinline__ void gload_lds16(const void* g, void* l) {
    __builtin_amdgcn_global_load_lds(
        (const __attribute__((address_space(1))) unsigned int*)g,
        (__attribute__((address_space(3))) unsigned int*)l, 16, 0, 0);
}

// ---------------------------------------------------------------------------
// cast: out[i] = bf16(in[i]), 8 elems/thread
// ---------------------------------------------------------------------------
__global__ __launch_bounds__(256) void cast_bf16_kernel(
    const float* __restrict__ in, unsigned short* __restrict__ out, long n8)
{
    long i = (long)blockIdx.x * 256 + threadIdx.x;
    long stride = (long)gridDim.x * 256;
    for (; i < n8; i += stride) {
        float4v a = reinterpret_cast<const float4v*>(in)[2 * i];
        float4v b = reinterpret_cast<const float4v*>(in)[2 * i + 1];
        ushortx8 h;
        #pragma unroll
        for (int q = 0; q < 4; ++q) { h[q] = f2bf(a[q]); h[4 + q] = f2bf(b[q]); }
        reinterpret_cast<ushortx8*>(out)[i] = h;
    }
}

// ---------------------------------------------------------------------------
// reduce2: out[i] = bf16(relu(p0[i]+p1[i])), 8 elems/thread
// ---------------------------------------------------------------------------
__global__ __launch_bounds__(256) void reduce_relu_kernel(
    const unsigned short* __restrict__ p0, const unsigned short* __restrict__ p1,
    unsigned short* __restrict__ out, long n8)
{
    long i = (long)blockIdx.x * 256 + threadIdx.x;
    long stride = (long)gridDim.x * 256;
    const ushortx8* a0 = reinterpret_cast<const ushortx8*>(p0);
    const ushortx8* a1 = reinterpret_cast<const ushortx8*>(p1);
    for (; i < n8; i += stride) {
        ushortx8 x = a0[i], y = a1[i];
        ushortx8 h;
        #pragma unroll
        for (int q = 0; q < 8; ++q)
            h[q] = f2bf(fmaxf(bf2f(x[q]) + bf2f(y[q]), 0.0f));
        reinterpret_cast<ushortx8*>(out)[i] = h;
    }
}

// ---------------------------------------------------------------------------
// prep: W1e[ci*90 + tap*10 + co] = w1[co,ci,di,dj]   (tap = di*3+dj)
//       w23[tap*10 + c10]        = sum_c5 w3[c5] * w2[c5,c10,di,dj]
// ---------------------------------------------------------------------------
__global__ __launch_bounds__(256) void prep_kernel(
    const float* __restrict__ w1, const float* __restrict__ w2,
    const float* __restrict__ w3, float* __restrict__ W1e,
    float* __restrict__ w23)
{
    for (int idx = threadIdx.x; idx < 4590; idx += 256) {
        int ci = idx / 90, rem = idx % 90;
        int tap = rem / 10, co = rem % 10;
        int di = tap / 3, dj = tap % 3;
        W1e[idx] = w1[((co * 51 + ci) * 3 + di) * 3 + dj];
    }
    if (threadIdx.x < 90) {
        int tap = threadIdx.x / 10, c10 = threadIdx.x % 10;
        int di = tap / 3, dj = tap % 3;
        float s = 0.f;
        #pragma unroll
        for (int c5 = 0; c5 < 5; ++c5)
            s = fmaf(w3[c5], w2[((c5 * 10 + c10) * 3 + di) * 3 + dj], s);
        w23[threadIdx.x] = s;
    }
}

// ---------------------------------------------------------------------------
// transpose_all: 4 weight transposes (f32 [R][C] -> bf16 [C][R]) in one
// launch; linear block id decodes matrix + (bx,by).
// ---------------------------------------------------------------------------
__global__ __launch_bounds__(256) void transpose_all(
    const float* __restrict__ Wc, const float* __restrict__ Wou1,
    const float* __restrict__ Wofc, const float* __restrict__ Wdec,
    unsigned short* __restrict__ Wcb, unsigned short* __restrict__ Wou1b,
    unsigned short* __restrict__ Wofcb, unsigned short* __restrict__ Wdecb)
{
    __shared__ float t[32][33];
    int id = blockIdx.x;
    const float* in; unsigned short* out; int R, C, bx, by;
    if (id < 4096)      { in = Wc;   out = Wcb;   R = 4096; C = 1024;
                          bx = id & 31;  by = id >> 5; }
    else if (id < 5120) { id -= 4096; in = Wou1; out = Wou1b; R = 1024; C = 1024;
                          bx = id & 31;  by = id >> 5; }
    else if (id < 6144) { id -= 5120; in = Wofc; out = Wofcb; R = 1024; C = 1024;
                          bx = id & 31;  by = id >> 5; }
    else                { id -= 6144; in = Wdec; out = Wdecb; R = 1024; C = 4096;
                          bx = id & 127; by = id >> 7; }
    const int tx = threadIdx.x & 31;
    const int ty = threadIdx.x >> 5;
    const int r0 = by * 32, c0 = bx * 32;
    #pragma unroll
    for (int k = 0; k < 4; ++k)
        t[ty + k * 8][tx] = in[(size_t)(r0 + ty + k * 8) * C + c0 + tx];
    __syncthreads();
    #pragma unroll
    for (int k = 0; k < 4; ++k)
        out[(size_t)(c0 + ty + k * 8) * R + r0 + tx] = f2bf(t[tx][ty + k * 8]);
}

// ---------------------------------------------------------------------------
// fp1: Fp1[p][t] = sum_ci freq[p][ci] * W1e[ci][t]
// ---------------------------------------------------------------------------
__global__ __launch_bounds__(256) void fp1_kernel(
    const float* __restrict__ freq, const float* __restrict__ W1e,
    float* __restrict__ Fp1)
{
    __shared__ float W1s[4590];
    for (int idx = threadIdx.x; idx < 4590; idx += 256)
        W1s[idx] = W1e[idx];
    __syncthreads();
    int p = blockIdx.x * 256 + threadIdx.x;
    if (p >= 22801) return;
    float2v acc[45];
    #pragma unroll
    for (int t = 0; t < 45; ++t) { acc[t][0] = 0.f; acc[t][1] = 0.f; }
    const float* fr = freq + (size_t)p * 51;
    for (int ci = 0; ci < 51; ++ci) {
        float v = fr[ci];
        const float2v* wrow = reinterpret_cast<const float2v*>(&W1s[ci * 90]);
        #pragma unroll
        for (int t = 0; t < 45; ++t) {
            float2v w = wrow[t];
            acc[t][0] = fmaf(v, w[0], acc[t][0]);
            acc[t][1] = fmaf(v, w[1], acc[t][1]);
        }
    }
    float2v* out = reinterpret_cast<float2v*>(Fp1 + (size_t)p * 90);
    #pragma unroll
    for (int t = 0; t < 45; ++t) out[t] = acc[t];
}

// ---------------------------------------------------------------------------
// gather: h1[b,pix][c10] = sum_{valid taps} Fp1[pair(i',j')][tap*10 + c10]
// ---------------------------------------------------------------------------
__global__ __launch_bounds__(320) void gather_kernel(
    const int* __restrict__ preds, const float* __restrict__ Fp1,
    float* __restrict__ h1)
{
    __shared__ int pb[80];
    const int b = blockIdx.y;
    const int tid = threadIdx.x;
    if (tid < 80) pb[tid] = preds[b * 80 + tid];
    __syncthreads();
    const int i = blockIdx.x * 4 + tid / 80;
    const int j = tid % 80;
    float2v acc[5];
    #pragma unroll
    for (int q = 0; q < 5; ++q) { acc[q][0] = 0.f; acc[q][1] = 0.f; }
    #pragma unroll
    for (int di = 0; di < 3; ++di) {
        int ii = i + di - 1;
        if (ii < 0 || ii >= 80) continue;
        int pi = pb[ii] * 151;
        #pragma unroll
        for (int dj = 0; dj < 3; ++dj) {
            int jj = j + dj - 1;
            if (jj < 0 || jj >= 80) continue;
            const float2v* row = reinterpret_cast<const float2v*>(
                Fp1 + (size_t)(pi + pb[jj]) * 90 + (di * 3 + dj) * 10);
            #pragma unroll
            for (int q = 0; q < 5; ++q) {
                float2v v = row[q];
                acc[q][0] += v[0];
                acc[q][1] += v[1];
            }
        }
    }
    float2v* out = reinterpret_cast<float2v*>(
        h1 + ((size_t)b * 6400 + i * 80 + j) * 10);
    #pragma unroll
    for (int q = 0; q < 5; ++q) out[q] = acc[q];
}

// ---------------------------------------------------------------------------
// conv23+degree fused: adj = sigmoid(conv over h1); block owns 4 full rows
// -> per-row LDS sum -> deg = rsqrt(1 + rowsum + 1e-5)
// ---------------------------------------------------------------------------
__global__ __launch_bounds__(320) void conv23_deg_kernel(
    const float* __restrict__ h1, const float* __restrict__ w23g,
    float* __restrict__ adj, float* __restrict__ deg)
{
    __shared__ float w23s[90];
    __shared__ float rowv[320];
    const int tid = threadIdx.x;
    if (tid < 90) w23s[tid] = w23g[tid];
    __syncthreads();
    const int b = blockIdx.y;
    const int i = blockIdx.x * 4 + tid / 80;
    const int j = tid % 80;
    float t = 0.f;
    #pragma unroll
    for (int di = 0; di < 3; ++di) {
        int ii = i + di - 1;
        if (ii < 0 || ii >= 80) continue;
        #pragma unroll
        for (int dj = 0; dj < 3; ++dj) {
            int jj = j + dj - 1;
            if (jj < 0 || jj >= 80) continue;
            const float2v* hp = reinterpret_cast<const float2v*>(
                h1 + ((size_t)b * 6400 + ii * 80 + jj) * 10);
            const float* wp = w23s + (di * 3 + dj) * 10;
            #pragma unroll
            for (int q = 0; q < 5; ++q) {
                float2v v = hp[q];
                t = fmaf(v[0], wp[2 * q], t);
                t = fmaf(v[1], wp[2 * q + 1], t);
            }
        }
    }
    float sig = 1.0f / (1.0f + __expf(-t));
    adj[(size_t)b * 6400 + i * 80 + j] = sig;
    rowv[tid] = sig;
    __syncthreads();
    if (tid < 4) {
        float s = 1.0f + 1e-5f;
        #pragma unroll 16
        for (int jj = 0; jj < 80; ++jj) s += rowv[tid * 80 + jj];
        deg[b * 80 + blockIdx.x * 4 + tid] = rsqrtf(s);
    }
}

// ---------------------------------------------------------------------------
// 64x128 GEMM, BK=32, 24 KiB LDS, full-drain dbuf: relu -> bf16.
// Used for the small K=1024 GEMMs (gemm2/gemm3): 640 blocks.
// ---------------------------------------------------------------------------
__global__ __launch_bounds__(256) void gemm64(
    const unsigned short* __restrict__ Ap, const unsigned short* __restrict__ Bt,
    unsigned short* __restrict__ Cp, int M, int N, int lda)
{
    __shared__ __align__(16) unsigned short SS[12288];   // 24 KiB
    unsigned short* Al = SS;          // [2][64*32]
    unsigned short* Bl = SS + 4096;   // [2][128*32]

    const int tid  = threadIdx.x;
    const int bm   = blockIdx.x * 64;
    const int bn   = blockIdx.y * 128;
    const int wave = tid >> 6;
    const int lane = tid & 63;
    const int wm   = (wave >> 1) * 32;
    const int wn   = (wave & 1) * 64;
    const int lr   = lane & 15;
    const int lo   = lane >> 4;
    const int soct = (lo ^ ((lr >> 1) & 3)) * 8;

    floatx4 acc[2][4];
    #pragma unroll
    for (int i = 0; i < 2; ++i)
        #pragma unroll
        for (int j = 0; j < 4; ++j)
            #pragma unroll
            for (int r = 0; r < 4; ++r) acc[i][j][r] = 0.0f;

    auto stage = [&](int buf, int kq) {
        {
            int r = tid >> 2, s = tid & 3;
            gload_lds16(
                &Ap[(size_t)(bm + r) * lda + kq + ((s ^ ((r >> 1) & 3)) * 8)],
                &Al[buf * 2048 + tid * 8]);
        }
        #pragma unroll
        for (int it = 0; it < 2; ++it) {
            int idx = tid + it * 256;
            int r = idx >> 2, s = idx & 3;
            gload_lds16(
                &Bt[(size_t)(bn + r) * lda + kq + ((s ^ ((r >> 1) & 3)) * 8)],
                &Bl[buf * 4096 + idx * 8]);
        }
    };

    stage(0, 0);
    __syncthreads();
    const int nt = lda >> 5;
    int cur = 0;
    for (int t = 0; t < nt; ++t) {
        if (t + 1 < nt) stage(cur ^ 1, (t + 1) << 5);
        bf16x8 af[2], bfv[4];
        #pragma unroll
        for (int mi = 0; mi < 2; ++mi)
            af[mi] = *reinterpret_cast<const bf16x8*>(
                &Al[cur * 2048 + (wm + mi * 16 + lr) * 32 + soct]);
        #pragma unroll
        for (int ni = 0; ni < 4; ++ni)
            bfv[ni] = *reinterpret_cast<const bf16x8*>(
                &Bl[cur * 4096 + (wn + ni * 16 + lr) * 32 + soct]);
        #pragma unroll
        for (int mi = 0; mi < 2; ++mi)
            #pragma unroll
            for (int ni = 0; ni < 4; ++ni)
                acc[mi][ni] = __builtin_amdgcn_mfma_f32_16x16x32_bf16(
                    bfv[ni], af[mi], acc[mi][ni], 0, 0, 0);
        __syncthreads();
        cur ^= 1;
    }

    #pragma unroll
    for (int mi = 0; mi < 2; ++mi) {
        const int mrow = wm + mi * 16 + lr;
        const int swz = (mrow & 7) << 4;
        #pragma unroll
        for (int ni = 0; ni < 4; ++ni) {
            const int nc = wn + ni * 16 + lo * 4;
            ushortx4 v;
            #pragma unroll
            for (int rr = 0; rr < 4; ++rr)
                v[rr] = f2bf(fmaxf(acc[mi][ni][rr], 0.f));
            *reinterpret_cast<ushortx4*>(
                (char*)SS + ((mrow * 256 + nc * 2) ^ swz)) = v;
        }
    }
    __syncthreads();
    #pragma unroll
    for (int it = 0; it < 4; ++it) {
        int idx = tid + it * 256;
        int r = idx >> 4, c = idx & 15;
        ushortx8 v = *reinterpret_cast<const ushortx8*>(
            (char*)SS + ((r * 256 + c * 16) ^ ((r & 7) << 4)));
        *reinterpret_cast<ushortx8*>(
            &Cp[(size_t)(bm + r) * N + bn + c * 8]) = v;
    }
}

// ---------------------------------------------------------------------------
// 128x128 GEMM, BK=32 — triple-buffered counted-vmcnt pipeline (best K-loop).
//   MODE 1: relu + bf16 residual Rb -> f32 (two 64-col passes)
//   MODE 2: raw bf16 partial -> (z ? P1 : Cp)   [k-range z*kh..z*kh+kh)
// ---------------------------------------------------------------------------
template<int MODE>
__global__ __launch_bounds__(256) void gemm8p(
    const unsigned short* __restrict__ Ap, const unsigned short* __restrict__ Bt,
    void* __restrict__ Cp, const unsigned short* __restrict__ Rb,
    unsigned short* __restrict__ P1,
    int M, int N, int lda, int kh)
{
    __shared__ __align__(16) unsigned short SS[24576];   // 48 KiB
    unsigned short* Al = SS;            // [3][128*32]
    unsigned short* Bl = SS + 12288;    // [3][128*32]

    const int tid  = threadIdx.x;
    const int bm   = blockIdx.x * 128;
    const int bn   = blockIdx.y * 128;
    const int k0   = blockIdx.z * kh;
    const int wave = tid >> 6;
    const int lane = tid & 63;
    const int wm   = (wave >> 1) * 64;
    const int wn   = (wave & 1) * 64;
    const int lr   = lane & 15;
    const int lo   = lane >> 4;
    const int soct = (lo ^ ((lr >> 1) & 3)) * 8;

    floatx4 acc[4][4];
    #pragma unroll
    for (int i = 0; i < 4; ++i)
        #pragma unroll
        for (int j = 0; j < 4; ++j)
            #pragma unroll
            for (int r = 0; r < 4; ++r) acc[i][j][r] = 0.0f;

    auto stageA = [&](int buf, int kq) {
        #pragma unroll
        for (int it = 0; it < 2; ++it) {
            int idx = tid + it * 256;
            int r = idx >> 2, s = idx & 3;
            gload_lds16(
                &Ap[(size_t)(bm + r) * lda + kq + ((s ^ ((r >> 1) & 3)) * 8)],
                &Al[buf * 4096 + idx * 8]);
        }
    };
    auto stageB = [&](int buf, int kq) {
        #pragma unroll
        for (int it = 0; it < 2; ++it) {
            int idx = tid + it * 256;
            int r = idx >> 2, s = idx & 3;
            gload_lds16(
                &Bt[(size_t)(bn + r) * lda + kq + ((s ^ ((r >> 1) & 3)) * 8)],
                &Bl[buf * 4096 + idx * 8]);
        }
    };

    const int nt = kh >> 5;
    stageA(0, k0);
    stageB(0, k0);
    if (nt > 1) stageA(1, k0 + 32);

    for (int t = 0; t < nt; ++t) {
        const int cur = t % 3;
        if (t + 1 < nt) {
            asm volatile("s_waitcnt vmcnt(2)" ::: "memory");
        } else {
            asm volatile("s_waitcnt vmcnt(0)" ::: "memory");
        }
        __builtin_amdgcn_s_barrier();
        __builtin_amdgcn_sched_barrier(0);

        bf16x8 af[4], bf0[2];
        #pragma unroll
        for (int mi = 0; mi < 4; ++mi)
            af[mi] = *reinterpret_cast<const bf16x8*>(
                &Al[cur * 4096 + (wm + mi * 16 + lr) * 32 + soct]);
        #pragma unroll
        for (int ni = 0; ni < 2; ++ni)
            bf0[ni] = *reinterpret_cast<const bf16x8*>(
                &Bl[cur * 4096 + (wn + ni * 16 + lr) * 32 + soct]);
        if (t + 1 < nt) stageB((t + 1) % 3, k0 + ((t + 1) << 5));
        __builtin_amdgcn_sched_barrier(0);
        __builtin_amdgcn_s_barrier();
        __builtin_amdgcn_s_setprio(1);
        #pragma unroll
        for (int mi = 0; mi < 4; ++mi)
            #pragma unroll
            for (int ni = 0; ni < 2; ++ni)
                acc[mi][ni] = __builtin_amdgcn_mfma_f32_16x16x32_bf16(
                    bf0[ni], af[mi], acc[mi][ni], 0, 0, 0);
        __builtin_amdgcn_s_setprio(0);

        bf16x8 bf1[2];
        #pragma unroll
        for (int ni = 0; ni < 2; ++ni)
            bf1[ni] = *reinterpret_cast<const bf16x8*>(
                &Bl[cur * 4096 + (wn + (ni + 2) * 16 + lr) * 32 + soct]);
        if (t + 2 < nt) stageA((t + 2) % 3, k0 + ((t + 2) << 5));
        __builtin_amdgcn_sched_barrier(0);
        __builtin_amdgcn_s_barrier();
        __builtin_amdgcn_s_setprio(1);
        #pragma unroll
        for (int mi = 0; mi < 4; ++mi)
            #pragma unroll
            for (int ni = 0; ni < 2; ++ni)
                acc[mi][ni + 2] = __builtin_amdgcn_mfma_f32_16x16x32_bf16(
                    bf1[ni], af[mi], acc[mi][ni + 2], 0, 0, 0);
        __builtin_amdgcn_s_setprio(0);
    }

    __syncthreads();
    if (MODE == 1) {
        #pragma unroll
        for (int p = 0; p < 2; ++p) {
            if ((wave & 1) == p) {
                #pragma unroll
                for (int mi = 0; mi < 4; ++mi) {
                    const int mrow = wm + mi * 16 + lr;
                    const int swz = (mrow & 7) << 4;
                    #pragma unroll
                    for (int ni = 0; ni < 4; ++ni) {
                        const int nc = ni * 16 + lo * 4;
                        float4v v;
                        #pragma unroll
                        for (int rr = 0; rr < 4; ++rr) v[rr] = acc[mi][ni][rr];
                        *reinterpret_cast<float4v*>(
                            (char*)SS + ((mrow * 256 + nc * 4) ^ swz)) = v;
                    }
                }
            }
            __syncthreads();
            #pragma unroll
            for (int it = 0; it < 8; ++it) {
                int idx = tid + it * 256;
                int r = idx >> 4, c = idx & 15;
                float4v v = *reinterpret_cast<const float4v*>(
                    (char*)SS + ((r * 256 + c * 16) ^ ((r & 7) << 4)));
                size_t off = (size_t)(bm + r) * N + bn + p * 64 + c * 4;
                ushortx4 rv = *reinterpret_cast<const ushortx4*>(&Rb[off]);
                float4v o;
                #pragma unroll
                for (int rr = 0; rr < 4; ++rr)
                    o[rr] = fmaxf(v[rr], 0.f) + bf2f(rv[rr]);
                *reinterpret_cast<float4v*>(&((float*)Cp)[off]) = o;
            }
            if (p == 0) __syncthreads();
        }
    } else {
        // MODE 2: raw bf16 partial, z-routed
        #pragma unroll
        for (int mi = 0; mi < 4; ++mi) {
            const int mrow = wm + mi * 16 + lr;
            const int swz = (mrow & 7) << 4;
            #pragma unroll
            for (int ni = 0; ni < 4; ++ni) {
                const int nc = wn + ni * 16 + lo * 4;
                ushortx4 v;
                #pragma unroll
                for (int rr = 0; rr < 4; ++rr)
                    v[rr] = f2bf(acc[mi][ni][rr]);
                *reinterpret_cast<ushortx4*>(
                    (char*)SS + ((mrow * 256 + nc * 2) ^ swz)) = v;
            }
        }
        __syncthreads();
        unsigned short* dst = blockIdx.z ? P1 : (unsigned short*)Cp;
        #pragma unroll
        for (int it = 0; it < 8; ++it) {
            int idx = tid + it * 256;
            int r = idx >> 4, c = idx & 15;
            ushortx8 v = *reinterpret_cast<const ushortx8*>(
                (char*)SS + ((r * 256 + c * 16) ^ ((r & 7) << 4)));
            *reinterpret_cast<ushortx8*>(
                &dst[(size_t)(bm + r) * N + bn + c * 8]) = v;
        }
    }
}

// ---------------------------------------------------------------------------
// Fallback GEMM (f32 A converted in staging) -> relu bf16 (ws-small path).
// ---------------------------------------------------------------------------
__global__ __launch_bounds__(256) void gemm_f32a(
    const float* __restrict__ Ap, const unsigned short* __restrict__ Bt,
    unsigned short* __restrict__ Cp, int M, int N, int lda)
{
    __shared__ unsigned short Al[2][128 * 40];
    __shared__ unsigned short Bl[2][128 * 32];
    const int tid  = threadIdx.x;
    const int bm   = blockIdx.x * 128;
    const int bn   = blockIdx.y * 128;
    const int wave = tid >> 6;
    const int lane = tid & 63;
    const int wm   = (wave >> 1) * 64;
    const int wn   = (wave & 1) * 64;
    const int lr   = lane & 15;
    const int lk   = (lane >> 4) * 8;
    floatx4 acc[4][4];
    #pragma unroll
    for (int i = 0; i < 4; ++i)
        #pragma unroll
        for (int j = 0; j < 4; ++j)
            #pragma unroll
            for (int r = 0; r < 4; ++r) acc[i][j][r] = 0.0f;
    auto stage = [&](int buf, int k0) {
        #pragma unroll
        for (int it = 0; it < 4; ++it) {
            int idx = tid + it * 256;
            int r = idx >> 3, kc = (idx & 7) * 4;
            float4v v = *reinterpret_cast<const float4v*>(
                &Ap[(size_t)(bm + r) * lda + k0 + kc]);
            ushortx4 h;
            #pragma unroll
            for (int q = 0; q < 4; ++q) h[q] = f2bf(v[q]);
            *reinterpret_cast<ushortx4*>(&Al[buf][r * 40 + kc]) = h;
        }
        #pragma unroll
        for (int it = 0; it < 2; ++it) {
            int idx = tid + it * 256;
            gload_lds16(&Bt[(size_t)(bn + (idx >> 2)) * lda + k0 + (idx & 3) * 8],
                        &Bl[buf][idx * 8]);
        }
    };
    stage(0, 0);
    __syncthreads();
    const int nt = lda >> 5;
    int cur = 0;
    for (int t = 0; t < nt; ++t) {
        if (t + 1 < nt) stage(cur ^ 1, (t + 1) << 5);
        bf16x8 af[4], bfv[4];
        #pragma unroll
        for (int mi = 0; mi < 4; ++mi)
            af[mi] = *reinterpret_cast<const bf16x8*>(
                &Al[cur][(wm + mi * 16 + lr) * 40 + lk]);
        #pragma unroll
        for (int ni = 0; ni < 4; ++ni)
            bfv[ni] = *reinterpret_cast<const bf16x8*>(
                &Bl[cur][(wn + ni * 16 + lr) * 32 + lk]);
        #pragma unroll
        for (int mi = 0; mi < 4; ++mi)
            #pragma unroll
            for (int ni = 0; ni < 4; ++ni)
                acc[mi][ni] = __builtin_amdgcn_mfma_f32_16x16x32_bf16(
                    af[mi], bfv[ni], acc[mi][ni], 0, 0, 0);
        __syncthreads();
        cur ^= 1;
    }
    #pragma unroll
    for (int mi = 0; mi < 4; ++mi)
        #pragma unroll
        for (int ni = 0; ni < 4; ++ni)
            #pragma unroll
            for (int r = 0; r < 4; ++r) {
                int row = bm + wm + mi * 16 + (lane >> 4) * 4 + r;
                int col = bn + wn + ni * 16 + lr;
                Cp[(size_t)row * N + col] = f2bf(fmaxf(acc[mi][ni][r], 0.f));
            }
}

// ---------------------------------------------------------------------------
// Fallback final GEMM with f32 residual (scattered epilogue) — ws-small path.
// ---------------------------------------------------------------------------
__global__ __launch_bounds__(256) void gemm_res_f32(
    const unsigned short* __restrict__ Ap, const unsigned short* __restrict__ Bt,
    float* __restrict__ Cp, const float* __restrict__ Rp, int M, int N, int lda)
{
    __shared__ unsigned short Al[2][128 * 32];
    __shared__ unsigned short Bl[2][128 * 32];
    const int tid  = threadIdx.x;
    const int bm   = blockIdx.x * 128;
    const int bn   = blockIdx.y * 128;
    const int wave = tid >> 6;
    const int lane = tid & 63;
    const int wm   = (wave >> 1) * 64;
    const int wn   = (wave & 1) * 64;
    const int lr   = lane & 15;
    const int lk   = (lane >> 4) * 8;
    floatx4 acc[4][4];
    #pragma unroll
    for (int i = 0; i < 4; ++i)
        #pragma unroll
        for (int j = 0; j < 4; ++j)
            #pragma unroll
            for (int r = 0; r < 4; ++r) acc[i][j][r] = 0.0f;
    auto stage = [&](int buf, int kq) {
        #pragma unroll
        for (int it = 0; it < 2; ++it) {
            int idx = tid + it * 256;
            gload_lds16(&Ap[(size_t)(bm + (idx >> 2)) * lda + kq + (idx & 3) * 8],
                        &Al[buf][idx * 8]);
        }
        #pragma unroll
        for (int it = 0; it < 2; ++it) {
            int idx = tid + it * 256;
            gload_lds16(&Bt[(size_t)(bn + (idx >> 2)) * lda + kq + (idx & 3) * 8],
                        &Bl[buf][idx * 8]);
        }
    };
    stage(0, 0);
    __syncthreads();
    const int nt = lda >> 5;
    int cur = 0;
    for (int t = 0; t < nt; ++t) {
        if (t + 1 < nt) stage(cur ^ 1, (t + 1) << 5);
        bf16x8 af[4], bfv[4];
        #pragma unroll
        for (int mi = 0; mi < 4; ++mi)
            af[mi] = *reinterpret_cast<const bf16x8*>(
                &Al[cur][(wm + mi * 16 + lr) * 32 + lk]);
        #pragma unroll
        for (int ni = 0; ni < 4; ++ni)
            bfv[ni] = *reinterpret_cast<const bf16x8*>(
                &Bl[cur][(wn + ni * 16 + lr) * 32 + lk]);
        #pragma unroll
        for (int mi = 0; mi < 4; ++mi)
            #pragma unroll
            for (int ni = 0; ni < 4; ++ni)
                acc[mi][ni] = __builtin_amdgcn_mfma_f32_16x16x32_bf16(
                    af[mi], bfv[ni], acc[mi][ni], 0, 0, 0);
        __syncthreads();
        cur ^= 1;
    }
    #pragma unroll
    for (int mi = 0; mi < 4; ++mi)
        #pragma unroll
        for (int ni = 0; ni < 4; ++ni)
            #pragma unroll
            for (int r = 0; r < 4; ++r) {
                int row = bm + wm + mi * 16 + (lane >> 4) * 4 + r;
                int col = bn + wn + ni * 16 + lr;
                size_t off = (size_t)row * N + col;
                Cp[off] = fmaxf(acc[mi][ni][r], 0.f) + Rp[off];
            }
}

// ---------------------------------------------------------------------------
// laplacian matmul: ofl[b,n,k] = d[n] * sum_m (adj[n,m]+I)*d[m] * u[m,k]
// ---------------------------------------------------------------------------
__global__ __launch_bounds__(256) void laplacian_kernel(
    const float* __restrict__ adj, const float* __restrict__ deg,
    const unsigned short* __restrict__ u_in, unsigned short* __restrict__ ofl)
{
    __shared__ float wl[6400];
    __shared__ unsigned short ul[80 * 256];
    const int b   = blockIdx.y;
    const int kq  = blockIdx.x;
    const int tid = threadIdx.x;
    const int ko  = tid & 31;
    const int ngrp = tid >> 5;

    const float* ab = adj + (size_t)b * 6400;
    const float* db = deg + b * 80;
    for (int idx = tid; idx < 6400; idx += 256) {
        int n = idx / 80;
        int m = idx - n * 80;
        float w = ab[idx] + (n == m ? 1.0f : 0.0f);
        wl[idx] = w * db[m];
    }
    const unsigned short* ub = u_in + (size_t)b * 80 * 1024 + kq * 256;
    #pragma unroll
    for (int it = 0; it < 10; ++it) {
        int idx = tid + it * 256;
        int m   = idx >> 5;
        int c8  = (idx & 31) * 8;
        *reinterpret_cast<ushortx8*>(&ul[m * 256 + c8]) =
            *reinterpret_cast<const ushortx8*>(&ub[(size_t)m * 1024 + c8]);
    }
    __syncthreads();

    float acc[10][8];
    #pragma unroll
    for (int ni = 0; ni < 10; ++ni)
        #pragma unroll
        for (int q = 0; q < 8; ++q) acc[ni][q] = 0.0f;

    for (int m = 0; m < 80; ++m) {
        ushortx8 uv = *reinterpret_cast<const ushortx8*>(&ul[m * 256 + ko * 8]);
        float uf[8];
        #pragma unroll
        for (int q = 0; q < 8; ++q) uf[q] = bf2f(uv[q]);
        #pragma unroll
        for (int ni = 0; ni < 10; ++ni) {
            float wv = wl[(ngrp * 10 + ni) * 80 + m];
            #pragma unroll
            for (int q = 0; q < 8; ++q)
                acc[ni][q] = fmaf(wv, uf[q], acc[ni][q]);
        }
    }
    #pragma unroll
    for (int ni = 0; ni < 10; ++ni) {
        int n = ngrp * 10 + ni;
        float dn = db[n];
        ushortx8 o;
        #pragma unroll
        for (int q = 0; q < 8; ++q) o[q] = f2bf(acc[ni][q] * dn);
        *reinterpret_cast<ushortx8*>(
            &ofl[((size_t)(b * 80 + n)) * 1024 + kq * 256 + ko * 8]) = o;
    }
}

// ---------------------------------------------------------------------------
extern "C" void kernel_launch(void* const* d_in, const int* in_sizes, int n_in,
                              void* d_out, int out_size, void* d_ws, size_t ws_size,
                              hipStream_t stream)
{
    const float* enc   = (const float*)d_in[0];   // [64,80,4096]
    const int*   preds = (const int*)d_in[1];     // [64,80]
    const float* freq  = (const float*)d_in[2];   // [22801,51]
    const float* Wc    = (const float*)d_in[3];   // [4096,1024]
    const float* Wou1  = (const float*)d_in[4];   // [1024,1024]
    const float* Wofc  = (const float*)d_in[5];   // [1024,1024]
    const float* Wdec  = (const float*)d_in[6];   // [1024,4096]
    const float* w1    = (const float*)d_in[7];   // [10,51,3,3]
    const float* w2    = (const float*)d_in[8];   // [5,10,3,3]
    const float* w3    = (const float*)d_in[9];   // [1,5,1,1]

    const int M = 5120;  // 64*80
    const size_t SLAB = (size_t)M * 1024;          // 5,242,880 elems
    unsigned short* comp  = (unsigned short*)d_ws; // [5120][1024] bf16
    unsigned short* obju  = comp + SLAB;
    unsigned short* r1    = obju + SLAB;           // 16,384,000 B region
    unsigned short* oflu  = r1;
    float*          h1    = (float*)r1;            // [64*6400][10] f32
    unsigned short* r2    = r1 + 8192000;          // 10,485,760 B region
    unsigned short* um    = r2;
    float*          Fp1   = (float*)r2;            // [22801][90] f32
    unsigned short* Wcb   = r2 + SLAB;             // [1024][4096]
    unsigned short* Wou1b = Wcb + (size_t)1024 * 4096;
    unsigned short* Wofcb = Wou1b + (size_t)1024 * 1024;
    unsigned short* Wdecb = Wofcb + (size_t)1024 * 1024;
    float*          W1e   = (float*)(Wdecb + (size_t)4096 * 1024);
    float*          w23   = W1e + 4590;
    float*          adj   = w23 + 90;              // [64][80][80]
    float*          deg   = adj + (size_t)64 * 6400;
    unsigned short* encb  = (unsigned short*)(deg + 5120); // [5120][4096] bf16
    const size_t need_bytes =
        ((size_t)(encb - comp) + (size_t)M * 4096) * sizeof(unsigned short);
    const bool use_encb = ws_size >= need_bytes;

    // --- weight prep (2 launches) ---
    prep_kernel<<<1, 256, 0, stream>>>(w1, w2, w3, W1e, w23);
    transpose_all<<<10240, 256, 0, stream>>>(
        Wc, Wou1, Wofc, Wdec, Wcb, Wou1b, Wofcb, Wdecb);

    // --- adjacency chain (3 launches; degree fused into conv23) ---
    fp1_kernel<<<90, 256, 0, stream>>>(freq, W1e, Fp1);
    gather_kernel<<<dim3(20, 64), 320, 0, stream>>>(preds, Fp1, h1);
    conv23_deg_kernel<<<dim3(20, 64), 320, 0, stream>>>(h1, w23, adj, deg);

    // --- main chain ---
    if (use_encb) {
        cast_bf16_kernel<<<2048, 256, 0, stream>>>(enc, encb, (long)M * 4096 / 8);
        // gemm1: split-K=2 on the counted-vmcnt pipeline (640 blocks)
        gemm8p<2><<<dim3(40, 8, 2), 256, 0, stream>>>(
            encb, Wcb, r1, nullptr, r2, M, 1024, 4096, 2048);
        reduce_relu_kernel<<<2048, 256, 0, stream>>>(r1, r2, comp, SLAB / 8);
        // gemm2/3: 64x128 tiles, 640 blocks single-shot
        gemm64<<<dim3(80, 8), 256, 0, stream>>>(comp, Wou1b, obju, M, 1024, 1024);
        laplacian_kernel<<<dim3(4, 64), 256, 0, stream>>>(adj, deg, obju, oflu);
        gemm64<<<dim3(80, 8), 256, 0, stream>>>(oflu, Wofcb, um, M, 1024, 1024);
        // gemm4: triple-buffer counted-vmcnt pipeline, bf16 residual
        gemm8p<1><<<dim3(40, 32, 1), 256, 0, stream>>>(
            um, Wdecb, d_out, encb, nullptr, M, 4096, 1024, 1024);
    } else {
        gemm_f32a<<<dim3(40, 8), 256, 0, stream>>>(enc, Wcb, comp, M, 1024, 4096);
        gemm64<<<dim3(80, 8), 256, 0, stream>>>(comp, Wou1b, obju, M, 1024, 1024);
        laplacian_kernel<<<dim3(4, 64), 256, 0, stream>>>(adj, deg, obju, oflu);
        gemm64<<<dim3(80, 8), 256, 0, stream>>>(oflu, Wofcb, um, M, 1024, 1024);
        gemm_res_f32<<<dim3(40, 32), 256, 0, stream>>>(
            um, Wdecb, (float*)d_out, enc, M, 4096, 1024);
    }
}